// Round 12
// baseline (537.265 us; speedup 1.0000x reference)
//
#include <hip/hip_runtime.h>
#include <hip/hip_bf16.h>

#define N_NODES 100000
#define N_EDGES 640000

typedef __bf16 bf16_t;
typedef __bf16 bf16x8 __attribute__((ext_vector_type(8)));
typedef float f32x4 __attribute__((ext_vector_type(4)));
typedef float f4 __attribute__((ext_vector_type(4)));
typedef unsigned int u32x4 __attribute__((ext_vector_type(4)));

__device__ __forceinline__ float bflo(unsigned int u) { return __uint_as_float(u << 16); }
__device__ __forceinline__ float bfhi(unsigned int u) { return __uint_as_float(u & 0xffff0000u); }
__device__ __forceinline__ unsigned int bfpack(float a, float b) {
    union { bf16_t h[2]; unsigned int u; } pk;
    pk.h[0] = (bf16_t)a; pk.h[1] = (bf16_t)b;
    return pk.u;
}

// ===========================================================================
// CSR build (hist -> hierarchical scan -> inverse permutation)
// ===========================================================================
__global__ void hist_kernel(const int* __restrict__ to_idx, int* __restrict__ hist) {
    int e = blockIdx.x * 256 + threadIdx.x;
    if (e < N_EDGES) atomicAdd(&hist[to_idx[e]], 1);
}

#define SCAN_CH 1000  // N_NODES = 100 blocks x 1000

__global__ __launch_bounds__(1024)
void scan_reduce_kernel(const int* __restrict__ hist, int* __restrict__ bsum) {
    __shared__ int red[1024];
    int b = blockIdx.x, t = threadIdx.x;
    int v = (t < SCAN_CH) ? hist[b * SCAN_CH + t] : 0;
    red[t] = v;
    __syncthreads();
    for (int off = 512; off > 0; off >>= 1) {
        if (t < off) red[t] += red[t + off];
        __syncthreads();
    }
    if (t == 0) bsum[b] = red[0];
}

__global__ __launch_bounds__(128)
void scan_base_kernel(const int* __restrict__ bsum, int* __restrict__ bbase) {
    __shared__ int s[128];
    int t = threadIdx.x;
    int v = (t < 100) ? bsum[t] : 0;
    s[t] = v;
    __syncthreads();
    for (int off = 1; off < 128; off <<= 1) {
        int u = (t >= off) ? s[t - off] : 0;
        __syncthreads();
        s[t] += u;
        __syncthreads();
    }
    if (t < 100) bbase[t] = s[t] - v;
}

__global__ __launch_bounds__(1024)
void scan_final_kernel(const int* __restrict__ hist,
                       const int* __restrict__ bbase,
                       int* __restrict__ cursor,
                       int* __restrict__ row_start) {
    __shared__ int s[1024];
    int b = blockIdx.x, t = threadIdx.x;
    int v = (t < SCAN_CH) ? hist[b * SCAN_CH + t] : 0;
    s[t] = v;
    __syncthreads();
    for (int off = 1; off < 1024; off <<= 1) {
        int u = (t >= off) ? s[t - off] : 0;
        __syncthreads();
        s[t] += u;
        __syncthreads();
    }
    int excl = bbase[b] + s[t] - v;
    if (t < SCAN_CH) {
        cursor[b * SCAN_CH + t] = excl;
        row_start[b * SCAN_CH + t] = excl;
    }
    if (b == 99 && t == SCAN_CH - 1) row_start[N_NODES] = excl + v;
}

__global__ void inv_scatter_kernel(const int* __restrict__ to_idx,
                                   int* __restrict__ cursor,
                                   int* __restrict__ inv) {
    int e = blockIdx.x * 256 + threadIdx.x;
    if (e < N_EDGES) {
        int pos = atomicAdd(&cursor[to_idx[e]], 1);
        inv[e] = pos;
    }
}

// ===========================================================================
// Factored GEMM. A[100K][256 u32] interleaved (msgpair, revpair) uint2:
//   F-half u32[2c]=msg pair c, u32[2c+1]=rev pair c; T-half at +128.
// Wt1 [512][128], WtE [256][128], WtU [128][128] pi-baked.
// ===========================================================================
__global__ void prep_w_new(const float* __restrict__ Wmsg,
                           const float* __restrict__ Wrev,
                           const float* __restrict__ Wupd,
                           bf16_t* __restrict__ Wt1,
                           bf16_t* __restrict__ WtE,
                           bf16_t* __restrict__ WtU) {
    int idx = blockIdx.x * 256 + threadIdx.x;
    if (idx < 512 * 128) {
        int p = idx >> 7, k = idx & 127;
        int blk = p >> 7, c = p & 127;
        float v;
        if (blk == 0)      v = Wmsg[k * 128 + c];
        else if (blk == 1) v = Wrev[k * 128 + c];
        else if (blk == 2) v = Wmsg[(128 + k) * 128 + c];
        else               v = Wrev[(128 + k) * 128 + c];
        Wt1[idx] = (bf16_t)v;
    }
    if (idx < 256 * 128) {
        int p = idx >> 7, k = idx & 127;
        float v = (p < 128) ? Wmsg[(256 + k) * 128 + p]
                            : Wrev[(256 + k) * 128 + (p - 128)];
        WtE[idx] = (bf16_t)v;
    }
    if (idx < 128 * 128) {
        int n = idx >> 7, p = idx & 127;
        int colp = 32 * (p >> 5) + ((p >> 1) & 15) + 16 * (p & 1);
        WtU[idx] = (bf16_t)Wupd[colp * 128 + n];
    }
}

// ---------------------------------------------------------------------------
// P1: A = node @ Wt1-half (streaming GEMM), stores interleaved uint2.
// ---------------------------------------------------------------------------
__global__ __launch_bounds__(512, 4)
void proj_node_kernel(const float* __restrict__ nodef,
                      const bf16_t* __restrict__ Wt1,
                      unsigned int* __restrict__ A_u) {
    __shared__ char lds_raw[64 * 256];  // [64][128] bf16, swizzled
    const int tid = threadIdx.x;
    const int nb = blockIdx.x * 64;
    const int by = blockIdx.y;  // 0=F, 1=T

#pragma unroll
    for (int j = 0; j < 4; ++j) {
        int linear = tid + 512 * j;
        int r = linear >> 5, q = linear & 31;
        int node = nb + r;
        f4 v = (f4){0.f, 0.f, 0.f, 0.f};
        if (node < N_NODES)
            v = *reinterpret_cast<const f4*>(nodef + (size_t)node * 128 + q * 4);
        union { bf16_t b[4]; uint2 u; } pk;
        pk.b[0] = (bf16_t)v[0]; pk.b[1] = (bf16_t)v[1];
        pk.b[2] = (bf16_t)v[2]; pk.b[3] = (bf16_t)v[3];
        int byte = (r * 256 + q * 8) ^ ((r & 7) << 4);
        *reinterpret_cast<uint2*>(lds_raw + byte) = pk.u;
    }
    __syncthreads();

    const int wv = tid >> 6;
    const int wr = wv >> 2, wc = wv & 3;
    const int lane = tid & 63;
    const int lhi = lane >> 4, llo = lane & 15;

    f32x4 acc[2][4];
#pragma unroll
    for (int m = 0; m < 2; ++m)
#pragma unroll
        for (int n = 0; n < 4; ++n)
            acc[m][n] = (f32x4){0.f, 0.f, 0.f, 0.f};

    const bf16_t* bptr[4];
#pragma unroll
    for (int n = 0; n < 4; ++n) {
        int colb = (n < 2) ? (wc * 32 + 16 * n) : (128 + wc * 32 + 16 * (n - 2));
        bptr[n] = Wt1 + (size_t)(by * 256 + colb + llo) * 128 + lhi * 8;
    }

#pragma unroll
    for (int k0 = 0; k0 < 4; ++k0) {
        bf16x8 a[2], b[4];
#pragma unroll
        for (int m = 0; m < 2; ++m) {
            int ra = wr * 32 + 16 * m + llo;
            int byte = (ra * 256 + (k0 * 32 + lhi * 8) * 2) ^ ((ra & 7) << 4);
            a[m] = *reinterpret_cast<const bf16x8*>(lds_raw + byte);
        }
#pragma unroll
        for (int n = 0; n < 4; ++n)
            b[n] = *reinterpret_cast<const bf16x8*>(bptr[n] + k0 * 32);
#pragma unroll
        for (int m = 0; m < 2; ++m)
#pragma unroll
            for (int n = 0; n < 4; ++n)
                acc[m][n] = __builtin_amdgcn_mfma_f32_16x16x32_bf16(a[m], b[n], acc[m][n], 0, 0, 0);
    }

    const int wli = wc * 16 + llo;
#pragma unroll
    for (int m = 0; m < 2; ++m) {
        int rbase = wr * 32 + 16 * m + lhi * 4;
#pragma unroll
        for (int r = 0; r < 4; ++r) {
            int node = nb + rbase + r;
            if (node < N_NODES) {
                size_t base = (size_t)node * 256 + by * 128;
                uint2 pr;
                pr.x = bfpack(acc[m][0][r], acc[m][1][r]);   // msg pair
                pr.y = bfpack(acc[m][2][r], acc[m][3][r]);   // rev pair
                *reinterpret_cast<uint2*>(A_u + base + 2 * wli) = pr;
            }
        }
    }
}

// ---------------------------------------------------------------------------
// T-DEFERRED edge kernel: per 32-edge block:
//   stage edgef (streaming) -> LDS, issue F-gathers ONLY (no T!),
//   MFMA K=128 (E-part), store PARTIAL = E + F + bias (pre-relu, msg/rev
//   separate bf16) at dst-sorted row inv[e]: 512 B/edge, full-line stores.
// Gather lines halved vs r10 (T moved to node_upd where it is sequential).
// ---------------------------------------------------------------------------
__global__ __launch_bounds__(256, 4)
void edge_fused_defT(const float* __restrict__ edgef,
                     const int* __restrict__ from_idx,
                     const int* __restrict__ inv,
                     const unsigned int* __restrict__ A_u,
                     const bf16_t* __restrict__ WtE,
                     const float* __restrict__ b_msg,
                     const float* __restrict__ b_rev,
                     unsigned int* __restrict__ msgs2) {
    __shared__ char lds_raw[32 * 256];  // [32][128] bf16, swizzled
    __shared__ int s_from[32], s_inv[32];

    const int tid = threadIdx.x;
    const int eb = blockIdx.x * 32;

    if (tid < 32) {
        s_from[tid] = from_idx[eb + tid];
        s_inv[tid]  = inv[eb + tid];
    }

#pragma unroll
    for (int j = 0; j < 4; ++j) {
        int linear = tid + 256 * j;
        int r = linear >> 5, q = linear & 31;
        f4 v = *reinterpret_cast<const f4*>(edgef + (size_t)(eb + r) * 128 + q * 4);
        union { bf16_t b[4]; uint2 u; } pk;
        pk.b[0] = (bf16_t)v[0]; pk.b[1] = (bf16_t)v[1];
        pk.b[2] = (bf16_t)v[2]; pk.b[3] = (bf16_t)v[3];
        int byte = (r * 256 + q * 8) ^ ((r & 7) << 4);
        *reinterpret_cast<uint2*>(lds_raw + byte) = pk.u;
    }
    __syncthreads();

    const int wc = tid >> 6;
    const int lane = tid & 63;
    const int lhi = lane >> 4, llo = lane & 15;
    const int wli = wc * 16 + llo;

    // F-gathers only; MFMA hides (part of) their latency
    uint2 gF[2][4];
#pragma unroll
    for (int m = 0; m < 2; ++m)
#pragma unroll
        for (int r = 0; r < 4; ++r) {
            int rr = 16 * m + lhi * 4 + r;
            gF[m][r] = *reinterpret_cast<const uint2*>(
                A_u + (size_t)s_from[rr] * 256 + 2 * wli);
        }

    f32x4 acc[2][4];
#pragma unroll
    for (int m = 0; m < 2; ++m)
#pragma unroll
        for (int n = 0; n < 4; ++n)
            acc[m][n] = (f32x4){0.f, 0.f, 0.f, 0.f};

    const bf16_t* bptr[4];
#pragma unroll
    for (int n = 0; n < 4; ++n) {
        int colb = (n < 2) ? (wc * 32 + 16 * n) : (128 + wc * 32 + 16 * (n - 2));
        bptr[n] = WtE + (size_t)(colb + llo) * 128 + lhi * 8;
    }

#pragma unroll
    for (int k0 = 0; k0 < 4; ++k0) {
        bf16x8 a[2], b[4];
#pragma unroll
        for (int m = 0; m < 2; ++m) {
            int ra = 16 * m + llo;
            int byte = (ra * 256 + (k0 * 32 + lhi * 8) * 2) ^ ((ra & 7) << 4);
            a[m] = *reinterpret_cast<const bf16x8*>(lds_raw + byte);
        }
#pragma unroll
        for (int n = 0; n < 4; ++n)
            b[n] = *reinterpret_cast<const bf16x8*>(bptr[n] + k0 * 32);
#pragma unroll
        for (int m = 0; m < 2; ++m)
#pragma unroll
            for (int n = 0; n < 4; ++n)
                acc[m][n] = __builtin_amdgcn_mfma_f32_16x16x32_bf16(a[m], b[n], acc[m][n], 0, 0, 0);
    }

    const int c0 = wc * 32 + llo;
    const float bm0 = b_msg[c0], bm1 = b_msg[c0 + 16];
    const float br0 = b_rev[c0], br1 = b_rev[c0 + 16];
#pragma unroll
    for (int m = 0; m < 2; ++m) {
#pragma unroll
        for (int r = 0; r < 4; ++r) {
            int rr = 16 * m + lhi * 4 + r;
            uint2 pw;
            pw.x = bfpack(acc[m][0][r] + bm0 + bflo(gF[m][r].x),
                          acc[m][1][r] + bm1 + bfhi(gF[m][r].x));   // msg partial pair
            pw.y = bfpack(acc[m][2][r] + br0 + bflo(gF[m][r].y),
                          acc[m][3][r] + br1 + bfhi(gF[m][r].y));   // rev partial pair
            *reinterpret_cast<uint2*>(msgs2 + (size_t)s_inv[rr] * 128 + 2 * wli) = pw;
        }
    }
}

// ---------------------------------------------------------------------------
// T-DEFERRED node update: per node, load A_T row ONCE (sequential), then per
// edge in its CSR range: msg = relu(partial_m + T_m) + relu(partial_r + T_r),
// f32 accumulate -> bf16 LDS (same stored-col order) -> MFMA w/ pi-baked WtU.
// ---------------------------------------------------------------------------
__global__ __launch_bounds__(256, 4)
void node_upd_defT(const unsigned int* __restrict__ msgs2,
                   const int* __restrict__ row_start,
                   const unsigned int* __restrict__ A_u,
                   const float* __restrict__ nodef,
                   const bf16_t* __restrict__ WtU,
                   const float* __restrict__ b_upd,
                   float* __restrict__ out) {
    __shared__ char lds_raw[64 * 256];
    __shared__ int s_rs[65];

    const int tid = threadIdx.x;
    const int nb = blockIdx.x * 64;

    if (tid < 65) {
        int nid = nb + tid;
        s_rs[tid] = (nid <= N_NODES) ? row_start[nid] : N_EDGES;
    }
    __syncthreads();

    {
        const int r = tid >> 2;      // node row 0..63
        const int q = tid & 3;       // 32-col chunk (16 pair-cols)
        // load this thread's slice of A_T[node]: 8 x u32x4, sequential
        u32x4 tw[8];
        int node = nb + r;
        if (node < N_NODES) {
            const u32x4* tp = reinterpret_cast<const u32x4*>(
                A_u + (size_t)node * 256 + 128 + q * 32);
#pragma unroll
            for (int j = 0; j < 8; ++j) tw[j] = tp[j];
        } else {
#pragma unroll
            for (int j = 0; j < 8; ++j) tw[j] = (u32x4){0, 0, 0, 0};
        }

        float s[32];
#pragma unroll
        for (int i = 0; i < 32; ++i) s[i] = 0.f;
        const int rs = s_rs[r], re = s_rs[r + 1];
        for (int e = rs; e < re; ++e) {
            const u32x4* p = reinterpret_cast<const u32x4*>(
                msgs2 + (size_t)e * 128 + q * 32);
#pragma unroll
            for (int j = 0; j < 8; ++j) {
                u32x4 v = p[j];
                // v[0]=msg pair w, v[1]=rev pair w, v[2]=msg pair w+1, v[3]=rev pair w+1
                float m0 = fmaxf(bflo(v[0]) + bflo(tw[j][0]), 0.f);
                float m1 = fmaxf(bfhi(v[0]) + bfhi(tw[j][0]), 0.f);
                float r0 = fmaxf(bflo(v[1]) + bflo(tw[j][1]), 0.f);
                float r1 = fmaxf(bfhi(v[1]) + bfhi(tw[j][1]), 0.f);
                float n0 = fmaxf(bflo(v[2]) + bflo(tw[j][2]), 0.f);
                float n1 = fmaxf(bfhi(v[2]) + bfhi(tw[j][2]), 0.f);
                float o0 = fmaxf(bflo(v[3]) + bflo(tw[j][3]), 0.f);
                float o1 = fmaxf(bfhi(v[3]) + bfhi(tw[j][3]), 0.f);
                int sbase = 8 * (j >> 1) + 4 * (j & 1);
                s[sbase + 0] += m0 + r0;
                s[sbase + 1] += m1 + r1;
                s[sbase + 2] += n0 + o0;
                s[sbase + 3] += n1 + o1;
            }
        }
#pragma unroll
        for (int i = 0; i < 4; ++i) {
            union { bf16_t b[8]; u32x4 u; } pk;
#pragma unroll
            for (int w = 0; w < 8; ++w) pk.b[w] = (bf16_t)s[8*i + w];
            int byte = (r * 256 + q * 64 + i * 16) ^ ((r & 7) << 4);
            *reinterpret_cast<u32x4*>(lds_raw + byte) = pk.u;
        }
    }
    __syncthreads();

    const int wv = tid >> 6;
    const int lane = tid & 63;
    const int lhi = lane >> 4, llo = lane & 15;

    f32x4 acc[4][2];
#pragma unroll
    for (int m = 0; m < 4; ++m)
#pragma unroll
        for (int n = 0; n < 2; ++n)
            acc[m][n] = (f32x4){0.f, 0.f, 0.f, 0.f};

#pragma unroll
    for (int k0 = 0; k0 < 4; ++k0) {
        bf16x8 a[4], b[2];
#pragma unroll
        for (int m = 0; m < 4; ++m) {
            int ra = 16 * m + llo;
            int byte = (ra * 256 + (k0 * 32 + lhi * 8) * 2) ^ ((ra & 7) << 4);
            a[m] = *reinterpret_cast<const bf16x8*>(lds_raw + byte);
        }
#pragma unroll
        for (int n = 0; n < 2; ++n) {
            int col = wv * 32 + 16 * n + llo;
            b[n] = *reinterpret_cast<const bf16x8*>(WtU + (size_t)col * 128 + k0 * 32 + lhi * 8);
        }
#pragma unroll
        for (int m = 0; m < 4; ++m)
#pragma unroll
            for (int n = 0; n < 2; ++n)
                acc[m][n] = __builtin_amdgcn_mfma_f32_16x16x32_bf16(a[m], b[n], acc[m][n], 0, 0, 0);
    }

#pragma unroll
    for (int m = 0; m < 4; ++m) {
        int rbase = 16 * m + lhi * 4;
#pragma unroll
        for (int r = 0; r < 4; ++r) {
            int i = nb + rbase + r;
            if (i < N_NODES) {
#pragma unroll
                for (int n = 0; n < 2; ++n) {
                    int c = wv * 32 + 16 * n + llo;
                    out[(size_t)i * 128 + c] =
                        nodef[(size_t)i * 128 + c]
                        + fmaxf(acc[m][n][r] + b_upd[c], 0.f);
                }
            }
        }
    }
}

// ===========================================================================
// FALLBACK (r10 path): full gathers in edge kernel, compact packed msgs.
// Used only if ws_size too small for the T-deferred layout.
// ===========================================================================
__global__ __launch_bounds__(256, 4)
void edge_fused_full(const float* __restrict__ edgef,
                     const int* __restrict__ from_idx,
                     const int* __restrict__ to_idx,
                     const int* __restrict__ inv,
                     const unsigned int* __restrict__ A_u,
                     const bf16_t* __restrict__ WtE,
                     const float* __restrict__ b_msg,
                     const float* __restrict__ b_rev,
                     unsigned int* __restrict__ msgs_u) {
    __shared__ char lds_raw[32 * 256];
    __shared__ int s_from[32], s_dst[32], s_inv[32];

    const int tid = threadIdx.x;
    const int eb = blockIdx.x * 32;

    if (tid < 32) {
        s_from[tid] = from_idx[eb + tid];
        s_dst[tid]  = to_idx[eb + tid];
        s_inv[tid]  = inv[eb + tid];
    }

#pragma unroll
    for (int j = 0; j < 4; ++j) {
        int linear = tid + 256 * j;
        int r = linear >> 5, q = linear & 31;
        f4 v = *reinterpret_cast<const f4*>(edgef + (size_t)(eb + r) * 128 + q * 4);
        union { bf16_t b[4]; uint2 u; } pk;
        pk.b[0] = (bf16_t)v[0]; pk.b[1] = (bf16_t)v[1];
        pk.b[2] = (bf16_t)v[2]; pk.b[3] = (bf16_t)v[3];
        int byte = (r * 256 + q * 8) ^ ((r & 7) << 4);
        *reinterpret_cast<uint2*>(lds_raw + byte) = pk.u;
    }
    __syncthreads();

    const int wc = tid >> 6;
    const int lane = tid & 63;
    const int lhi = lane >> 4, llo = lane & 15;
    const int wli = wc * 16 + llo;

    uint2 gF[2][4], gT[2][4];
#pragma unroll
    for (int m = 0; m < 2; ++m)
#pragma unroll
        for (int r = 0; r < 4; ++r) {
            int rr = 16 * m + lhi * 4 + r;
            gF[m][r] = *reinterpret_cast<const uint2*>(
                A_u + (size_t)s_from[rr] * 256 + 2 * wli);
            gT[m][r] = *reinterpret_cast<const uint2*>(
                A_u + (size_t)s_dst[rr] * 256 + 128 + 2 * wli);
        }

    f32x4 acc[2][4];
#pragma unroll
    for (int m = 0; m < 2; ++m)
#pragma unroll
        for (int n = 0; n < 4; ++n)
            acc[m][n] = (f32x4){0.f, 0.f, 0.f, 0.f};

    const bf16_t* bptr[4];
#pragma unroll
    for (int n = 0; n < 4; ++n) {
        int colb = (n < 2) ? (wc * 32 + 16 * n) : (128 + wc * 32 + 16 * (n - 2));
        bptr[n] = WtE + (size_t)(colb + llo) * 128 + lhi * 8;
    }

#pragma unroll
    for (int k0 = 0; k0 < 4; ++k0) {
        bf16x8 a[2], b[4];
#pragma unroll
        for (int m = 0; m < 2; ++m) {
            int ra = 16 * m + llo;
            int byte = (ra * 256 + (k0 * 32 + lhi * 8) * 2) ^ ((ra & 7) << 4);
            a[m] = *reinterpret_cast<const bf16x8*>(lds_raw + byte);
        }
#pragma unroll
        for (int n = 0; n < 4; ++n)
            b[n] = *reinterpret_cast<const bf16x8*>(bptr[n] + k0 * 32);
#pragma unroll
        for (int m = 0; m < 2; ++m)
#pragma unroll
            for (int n = 0; n < 4; ++n)
                acc[m][n] = __builtin_amdgcn_mfma_f32_16x16x32_bf16(a[m], b[n], acc[m][n], 0, 0, 0);
    }

    const int c0 = wc * 32 + llo;
    const float bm0 = b_msg[c0], bm1 = b_msg[c0 + 16];
    const float br0 = b_rev[c0], br1 = b_rev[c0 + 16];
#pragma unroll
    for (int m = 0; m < 2; ++m) {
#pragma unroll
        for (int r = 0; r < 4; ++r) {
            int rr = 16 * m + lhi * 4 + r;
            float m0 = fmaxf(acc[m][0][r] + bm0 + bflo(gF[m][r].x) + bflo(gT[m][r].x), 0.f);
            float m1 = fmaxf(acc[m][1][r] + bm1 + bfhi(gF[m][r].x) + bfhi(gT[m][r].x), 0.f);
            float r0 = fmaxf(acc[m][2][r] + br0 + bflo(gF[m][r].y) + bflo(gT[m][r].y), 0.f);
            float r1 = fmaxf(acc[m][3][r] + br1 + bfhi(gF[m][r].y) + bfhi(gT[m][r].y), 0.f);
            msgs_u[(size_t)s_inv[rr] * 64 + wli] = bfpack(m0 + r0, m1 + r1);
        }
    }
}

__global__ __launch_bounds__(256, 4)
void node_upd_pk(const unsigned int* __restrict__ msgs_u,
                 const int* __restrict__ row_start,
                 const float* __restrict__ nodef,
                 const bf16_t* __restrict__ WtU,
                 const float* __restrict__ b_upd,
                 float* __restrict__ out) {
    __shared__ char lds_raw[64 * 256];
    __shared__ int s_rs[65];

    const int tid = threadIdx.x;
    const int nb = blockIdx.x * 64;

    if (tid < 65) {
        int nid = nb + tid;
        s_rs[tid] = (nid <= N_NODES) ? row_start[nid] : N_EDGES;
    }
    __syncthreads();

    {
        const int r = tid >> 2;
        const int q = tid & 3;
        float s[32];
#pragma unroll
        for (int i = 0; i < 32; ++i) s[i] = 0.f;
        const int rs = s_rs[r], re = s_rs[r + 1];
        for (int e = rs; e < re; ++e) {
            const u32x4* p = reinterpret_cast<const u32x4*>(msgs_u + (size_t)e * 64 + q * 16);
#pragma unroll
            for (int i = 0; i < 4; ++i) {
                u32x4 w = p[i];
                s[8*i+0] += bflo(w[0]); s[8*i+1] += bfhi(w[0]);
                s[8*i+2] += bflo(w[1]); s[8*i+3] += bfhi(w[1]);
                s[8*i+4] += bflo(w[2]); s[8*i+5] += bfhi(w[2]);
                s[8*i+6] += bflo(w[3]); s[8*i+7] += bfhi(w[3]);
            }
        }
#pragma unroll
        for (int i = 0; i < 4; ++i) {
            union { bf16_t b[8]; u32x4 u; } pk;
#pragma unroll
            for (int w = 0; w < 8; ++w) pk.b[w] = (bf16_t)s[8*i + w];
            int byte = (r * 256 + q * 64 + i * 16) ^ ((r & 7) << 4);
            *reinterpret_cast<u32x4*>(lds_raw + byte) = pk.u;
        }
    }
    __syncthreads();

    const int wv = tid >> 6;
    const int lane = tid & 63;
    const int lhi = lane >> 4, llo = lane & 15;

    f32x4 acc[4][2];
#pragma unroll
    for (int m = 0; m < 4; ++m)
#pragma unroll
        for (int n = 0; n < 2; ++n)
            acc[m][n] = (f32x4){0.f, 0.f, 0.f, 0.f};

#pragma unroll
    for (int k0 = 0; k0 < 4; ++k0) {
        bf16x8 a[4], b[2];
#pragma unroll
        for (int m = 0; m < 4; ++m) {
            int ra = 16 * m + llo;
            int byte = (ra * 256 + (k0 * 32 + lhi * 8) * 2) ^ ((ra & 7) << 4);
            a[m] = *reinterpret_cast<const bf16x8*>(lds_raw + byte);
        }
#pragma unroll
        for (int n = 0; n < 2; ++n) {
            int col = wv * 32 + 16 * n + llo;
            b[n] = *reinterpret_cast<const bf16x8*>(WtU + (size_t)col * 128 + k0 * 32 + lhi * 8);
        }
#pragma unroll
        for (int m = 0; m < 4; ++m)
#pragma unroll
            for (int n = 0; n < 2; ++n)
                acc[m][n] = __builtin_amdgcn_mfma_f32_16x16x32_bf16(a[m], b[n], acc[m][n], 0, 0, 0);
    }

#pragma unroll
    for (int m = 0; m < 4; ++m) {
        int rbase = 16 * m + lhi * 4;
#pragma unroll
        for (int r = 0; r < 4; ++r) {
            int i = nb + rbase + r;
            if (i < N_NODES) {
#pragma unroll
                for (int n = 0; n < 2; ++n) {
                    int c = wv * 32 + 16 * n + llo;
                    out[(size_t)i * 128 + c] =
                        nodef[(size_t)i * 128 + c]
                        + fmaxf(acc[m][n][r] + b_upd[c], 0.f);
                }
            }
        }
    }
}

// ===========================================================================
extern "C" void kernel_launch(void* const* d_in, const int* in_sizes, int n_in,
                              void* d_out, int out_size, void* d_ws, size_t ws_size,
                              hipStream_t stream) {
    const float* nodef    = (const float*)d_in[0];
    const float* edgef    = (const float*)d_in[1];
    const int*   from_idx = (const int*)d_in[2];
    const int*   to_idx   = (const int*)d_in[3];
    const float* Wmsg     = (const float*)d_in[4];
    const float* bmsg     = (const float*)d_in[5];
    const float* Wrev     = (const float*)d_in[6];
    const float* brev     = (const float*)d_in[7];
    const float* Wupd     = (const float*)d_in[8];
    const float* bupd     = (const float*)d_in[9];
    float* out = (float*)d_out;
    char* ws = (char*)d_ws;

    if (ws_size >= 435000000) {
        // -------- T-deferred path --------
        unsigned int* A_u      = (unsigned int*)ws;               // 102,400,000
        unsigned int* msgs2    = (unsigned int*)(ws + 102400000); // 327,680,000
        bf16_t*       Wt1      = (bf16_t*)(ws + 430080000);       // 131,072
        bf16_t*       WtE      = (bf16_t*)(ws + 430211072);       // 65,536
        bf16_t*       WtU      = (bf16_t*)(ws + 430276608);       // 32,768
        int*          hist     = (int*)(ws + 430309376);          // 400,000
        int*          cursor   = (int*)(ws + 430709376);          // 400,000
        int*          rowstart = (int*)(ws + 431109376);          // 400,016
        int*          inv      = (int*)(ws + 431509392);          // 2,560,000
        int*          bsum     = (int*)(ws + 434069392);          // 400
        int*          bbase    = (int*)(ws + 434069792);          // 400

        hipMemsetAsync(hist, 0, (size_t)N_NODES * sizeof(int), stream);
        prep_w_new<<<256, 256, 0, stream>>>(Wmsg, Wrev, Wupd, Wt1, WtE, WtU);
        hist_kernel<<<(N_EDGES + 255) / 256, 256, 0, stream>>>(to_idx, hist);
        scan_reduce_kernel<<<100, 1024, 0, stream>>>(hist, bsum);
        scan_base_kernel<<<1, 128, 0, stream>>>(bsum, bbase);
        scan_final_kernel<<<100, 1024, 0, stream>>>(hist, bbase, cursor, rowstart);
        inv_scatter_kernel<<<(N_EDGES + 255) / 256, 256, 0, stream>>>(to_idx, cursor, inv);
        proj_node_kernel<<<dim3((N_NODES + 63) / 64, 2), 512, 0, stream>>>(nodef, Wt1, A_u);
        edge_fused_defT<<<N_EDGES / 32, 256, 0, stream>>>(
            edgef, from_idx, inv, A_u, WtE, bmsg, brev, msgs2);
        node_upd_defT<<<(N_NODES + 63) / 64, 256, 0, stream>>>(
            msgs2, rowstart, A_u, nodef, WtU, bupd, out);
    } else {
        // -------- r10 fallback --------
        unsigned int* A_u      = (unsigned int*)ws;               // 102,400,000
        unsigned int* msgs_u   = (unsigned int*)(ws + 102400000); // 163,840,000
        bf16_t*       Wt1      = (bf16_t*)(ws + 266240000);       // 131,072
        bf16_t*       WtE      = (bf16_t*)(ws + 266371072);       // 65,536
        bf16_t*       WtU      = (bf16_t*)(ws + 266436608);       // 32,768
        int*          hist     = (int*)(ws + 266469376);          // 400,000
        int*          cursor   = (int*)(ws + 266869376);          // 400,000
        int*          rowstart = (int*)(ws + 267269376);          // 400,016
        int*          inv      = (int*)(ws + 267669392);          // 2,560,000
        int*          bsum     = (int*)(ws + 270229392);          // 400
        int*          bbase    = (int*)(ws + 270229792);          // 400

        hipMemsetAsync(hist, 0, (size_t)N_NODES * sizeof(int), stream);
        prep_w_new<<<256, 256, 0, stream>>>(Wmsg, Wrev, Wupd, Wt1, WtE, WtU);
        hist_kernel<<<(N_EDGES + 255) / 256, 256, 0, stream>>>(to_idx, hist);
        scan_reduce_kernel<<<100, 1024, 0, stream>>>(hist, bsum);
        scan_base_kernel<<<1, 128, 0, stream>>>(bsum, bbase);
        scan_final_kernel<<<100, 1024, 0, stream>>>(hist, bbase, cursor, rowstart);
        inv_scatter_kernel<<<(N_EDGES + 255) / 256, 256, 0, stream>>>(to_idx, cursor, inv);
        proj_node_kernel<<<dim3((N_NODES + 63) / 64, 2), 512, 0, stream>>>(nodef, Wt1, A_u);
        edge_fused_full<<<N_EDGES / 32, 256, 0, stream>>>(
            edgef, from_idx, to_idx, inv, A_u, WtE, bmsg, brev, msgs_u);
        node_upd_pk<<<(N_NODES + 63) / 64, 256, 0, stream>>>(
            msgs_u, rowstart, nodef, WtU, bupd, out);
    }
}

// Round 13
// 446.097 us; speedup vs baseline: 1.2044x; 1.2044x over previous
//
#include <hip/hip_runtime.h>
#include <hip/hip_bf16.h>

#define N_NODES 100000
#define N_EDGES 640000

typedef __bf16 bf16_t;
typedef __bf16 bf16x8 __attribute__((ext_vector_type(8)));
typedef float f32x4 __attribute__((ext_vector_type(4)));
typedef float f4 __attribute__((ext_vector_type(4)));
typedef unsigned int u32x4 __attribute__((ext_vector_type(4)));

__device__ __forceinline__ float bflo(unsigned int u) { return __uint_as_float(u << 16); }
__device__ __forceinline__ float bfhi(unsigned int u) { return __uint_as_float(u & 0xffff0000u); }
__device__ __forceinline__ unsigned int bfpack(float a, float b) {
    union { bf16_t h[2]; unsigned int u; } pk;
    pk.h[0] = (bf16_t)a; pk.h[1] = (bf16_t)b;
    return pk.u;
}

// ===========================================================================
// CSR build (hist -> hierarchical scan -> inverse permutation)
// ===========================================================================
__global__ void hist_kernel(const int* __restrict__ to_idx, int* __restrict__ hist) {
    int e = blockIdx.x * 256 + threadIdx.x;
    if (e < N_EDGES) atomicAdd(&hist[to_idx[e]], 1);
}

#define SCAN_CH 1000  // N_NODES = 100 blocks x 1000

__global__ __launch_bounds__(1024)
void scan_reduce_kernel(const int* __restrict__ hist, int* __restrict__ bsum) {
    __shared__ int red[1024];
    int b = blockIdx.x, t = threadIdx.x;
    int v = (t < SCAN_CH) ? hist[b * SCAN_CH + t] : 0;
    red[t] = v;
    __syncthreads();
    for (int off = 512; off > 0; off >>= 1) {
        if (t < off) red[t] += red[t + off];
        __syncthreads();
    }
    if (t == 0) bsum[b] = red[0];
}

__global__ __launch_bounds__(128)
void scan_base_kernel(const int* __restrict__ bsum, int* __restrict__ bbase) {
    __shared__ int s[128];
    int t = threadIdx.x;
    int v = (t < 100) ? bsum[t] : 0;
    s[t] = v;
    __syncthreads();
    for (int off = 1; off < 128; off <<= 1) {
        int u = (t >= off) ? s[t - off] : 0;
        __syncthreads();
        s[t] += u;
        __syncthreads();
    }
    if (t < 100) bbase[t] = s[t] - v;
}

__global__ __launch_bounds__(1024)
void scan_final_kernel(const int* __restrict__ hist,
                       const int* __restrict__ bbase,
                       int* __restrict__ cursor,
                       int* __restrict__ row_start) {
    __shared__ int s[1024];
    int b = blockIdx.x, t = threadIdx.x;
    int v = (t < SCAN_CH) ? hist[b * SCAN_CH + t] : 0;
    s[t] = v;
    __syncthreads();
    for (int off = 1; off < 1024; off <<= 1) {
        int u = (t >= off) ? s[t - off] : 0;
        __syncthreads();
        s[t] += u;
        __syncthreads();
    }
    int excl = bbase[b] + s[t] - v;
    if (t < SCAN_CH) {
        cursor[b * SCAN_CH + t] = excl;
        row_start[b * SCAN_CH + t] = excl;
    }
    if (b == 99 && t == SCAN_CH - 1) row_start[N_NODES] = excl + v;
}

__global__ void inv_scatter_kernel(const int* __restrict__ to_idx,
                                   int* __restrict__ cursor,
                                   int* __restrict__ inv) {
    int e = blockIdx.x * 256 + threadIdx.x;
    if (e < N_EDGES) {
        int pos = atomicAdd(&cursor[to_idx[e]], 1);
        inv[e] = pos;
    }
}

// ===========================================================================
// Factored GEMM. A[100K][256 u32] interleaved (msgpair, revpair) uint2:
//   F-half u32[2c]=msg pair c, u32[2c+1]=rev pair c; T-half at +128.
// Wt1 [512][128], WtE [256][128], WtU [128][128] pi-baked.
// ===========================================================================
__global__ void prep_w_new(const float* __restrict__ Wmsg,
                           const float* __restrict__ Wrev,
                           const float* __restrict__ Wupd,
                           bf16_t* __restrict__ Wt1,
                           bf16_t* __restrict__ WtE,
                           bf16_t* __restrict__ WtU) {
    int idx = blockIdx.x * 256 + threadIdx.x;
    if (idx < 512 * 128) {
        int p = idx >> 7, k = idx & 127;
        int blk = p >> 7, c = p & 127;
        float v;
        if (blk == 0)      v = Wmsg[k * 128 + c];
        else if (blk == 1) v = Wrev[k * 128 + c];
        else if (blk == 2) v = Wmsg[(128 + k) * 128 + c];
        else               v = Wrev[(128 + k) * 128 + c];
        Wt1[idx] = (bf16_t)v;
    }
    if (idx < 256 * 128) {
        int p = idx >> 7, k = idx & 127;
        float v = (p < 128) ? Wmsg[(256 + k) * 128 + p]
                            : Wrev[(256 + k) * 128 + (p - 128)];
        WtE[idx] = (bf16_t)v;
    }
    if (idx < 128 * 128) {
        int n = idx >> 7, p = idx & 127;
        int colp = 32 * (p >> 5) + ((p >> 1) & 15) + 16 * (p & 1);
        WtU[idx] = (bf16_t)Wupd[colp * 128 + n];
    }
}

// ---------------------------------------------------------------------------
// P1: A = node @ Wt1-half (streaming GEMM), stores interleaved uint2.
// ---------------------------------------------------------------------------
__global__ __launch_bounds__(512, 4)
void proj_node_kernel(const float* __restrict__ nodef,
                      const bf16_t* __restrict__ Wt1,
                      unsigned int* __restrict__ A_u) {
    __shared__ char lds_raw[64 * 256];  // [64][128] bf16, swizzled
    const int tid = threadIdx.x;
    const int nb = blockIdx.x * 64;
    const int by = blockIdx.y;  // 0=F, 1=T

#pragma unroll
    for (int j = 0; j < 4; ++j) {
        int linear = tid + 512 * j;
        int r = linear >> 5, q = linear & 31;
        int node = nb + r;
        f4 v = (f4){0.f, 0.f, 0.f, 0.f};
        if (node < N_NODES)
            v = *reinterpret_cast<const f4*>(nodef + (size_t)node * 128 + q * 4);
        union { bf16_t b[4]; uint2 u; } pk;
        pk.b[0] = (bf16_t)v[0]; pk.b[1] = (bf16_t)v[1];
        pk.b[2] = (bf16_t)v[2]; pk.b[3] = (bf16_t)v[3];
        int byte = (r * 256 + q * 8) ^ ((r & 7) << 4);
        *reinterpret_cast<uint2*>(lds_raw + byte) = pk.u;
    }
    __syncthreads();

    const int wv = tid >> 6;
    const int wr = wv >> 2, wc = wv & 3;
    const int lane = tid & 63;
    const int lhi = lane >> 4, llo = lane & 15;

    f32x4 acc[2][4];
#pragma unroll
    for (int m = 0; m < 2; ++m)
#pragma unroll
        for (int n = 0; n < 4; ++n)
            acc[m][n] = (f32x4){0.f, 0.f, 0.f, 0.f};

    const bf16_t* bptr[4];
#pragma unroll
    for (int n = 0; n < 4; ++n) {
        int colb = (n < 2) ? (wc * 32 + 16 * n) : (128 + wc * 32 + 16 * (n - 2));
        bptr[n] = Wt1 + (size_t)(by * 256 + colb + llo) * 128 + lhi * 8;
    }

#pragma unroll
    for (int k0 = 0; k0 < 4; ++k0) {
        bf16x8 a[2], b[4];
#pragma unroll
        for (int m = 0; m < 2; ++m) {
            int ra = wr * 32 + 16 * m + llo;
            int byte = (ra * 256 + (k0 * 32 + lhi * 8) * 2) ^ ((ra & 7) << 4);
            a[m] = *reinterpret_cast<const bf16x8*>(lds_raw + byte);
        }
#pragma unroll
        for (int n = 0; n < 4; ++n)
            b[n] = *reinterpret_cast<const bf16x8*>(bptr[n] + k0 * 32);
#pragma unroll
        for (int m = 0; m < 2; ++m)
#pragma unroll
            for (int n = 0; n < 4; ++n)
                acc[m][n] = __builtin_amdgcn_mfma_f32_16x16x32_bf16(a[m], b[n], acc[m][n], 0, 0, 0);
    }

    const int wli = wc * 16 + llo;
#pragma unroll
    for (int m = 0; m < 2; ++m) {
        int rbase = wr * 32 + 16 * m + lhi * 4;
#pragma unroll
        for (int r = 0; r < 4; ++r) {
            int node = nb + rbase + r;
            if (node < N_NODES) {
                size_t base = (size_t)node * 256 + by * 128;
                uint2 pr;
                pr.x = bfpack(acc[m][0][r], acc[m][1][r]);   // msg pair
                pr.y = bfpack(acc[m][2][r], acc[m][3][r]);   // rev pair
                *reinterpret_cast<uint2*>(A_u + base + 2 * wli) = pr;
            }
        }
    }
}

// ---------------------------------------------------------------------------
// edge_fused (r10 structure + NT edgef loads): per 32-edge block:
//   stage edgef -> LDS with NON-TEMPORAL loads (read-once stream: do not
//   allocate in L3, preserve it for the 102MB A gather footprint),
//   issue F+T gathers, MFMA K=128, relu-combine, COMPACT packed store at inv.
// NT is applied to LOADS only; r5 lesson: NT stores on partial lines = 27x
// write amplification. Loads are full-line and read-once -> safe.
// ---------------------------------------------------------------------------
__global__ __launch_bounds__(256, 4)
void edge_fused_kernel(const float* __restrict__ edgef,
                       const int* __restrict__ from_idx,
                       const int* __restrict__ to_idx,
                       const int* __restrict__ inv,
                       const unsigned int* __restrict__ A_u,
                       const bf16_t* __restrict__ WtE,
                       const float* __restrict__ b_msg,
                       const float* __restrict__ b_rev,
                       unsigned int* __restrict__ msgs_u) {
    __shared__ char lds_raw[32 * 256];  // [32][128] bf16, swizzled
    __shared__ int s_from[32], s_dst[32], s_inv[32];

    const int tid = threadIdx.x;
    const int eb = blockIdx.x * 32;

    if (tid < 32) {
        s_from[tid] = from_idx[eb + tid];
        s_dst[tid]  = to_idx[eb + tid];
        s_inv[tid]  = inv[eb + tid];
    }

    // stage edgef (streaming, read-once): NON-TEMPORAL loads
#pragma unroll
    for (int j = 0; j < 4; ++j) {
        int linear = tid + 256 * j;
        int r = linear >> 5, q = linear & 31;
        f4 v = __builtin_nontemporal_load(
            reinterpret_cast<const f4*>(edgef + (size_t)(eb + r) * 128 + q * 4));
        union { bf16_t b[4]; uint2 u; } pk;
        pk.b[0] = (bf16_t)v[0]; pk.b[1] = (bf16_t)v[1];
        pk.b[2] = (bf16_t)v[2]; pk.b[3] = (bf16_t)v[3];
        int byte = (r * 256 + q * 8) ^ ((r & 7) << 4);
        *reinterpret_cast<uint2*>(lds_raw + byte) = pk.u;
    }
    __syncthreads();

    const int wc = tid >> 6;
    const int lane = tid & 63;
    const int lhi = lane >> 4, llo = lane & 15;
    const int wli = wc * 16 + llo;

    // F+T gathers (footprint 102MB; goal: L3-resident once edgef bypasses)
    uint2 gF[2][4], gT[2][4];
#pragma unroll
    for (int m = 0; m < 2; ++m)
#pragma unroll
        for (int r = 0; r < 4; ++r) {
            int rr = 16 * m + lhi * 4 + r;
            gF[m][r] = *reinterpret_cast<const uint2*>(
                A_u + (size_t)s_from[rr] * 256 + 2 * wli);
            gT[m][r] = *reinterpret_cast<const uint2*>(
                A_u + (size_t)s_dst[rr] * 256 + 128 + 2 * wli);
        }

    f32x4 acc[2][4];
#pragma unroll
    for (int m = 0; m < 2; ++m)
#pragma unroll
        for (int n = 0; n < 4; ++n)
            acc[m][n] = (f32x4){0.f, 0.f, 0.f, 0.f};

    const bf16_t* bptr[4];
#pragma unroll
    for (int n = 0; n < 4; ++n) {
        int colb = (n < 2) ? (wc * 32 + 16 * n) : (128 + wc * 32 + 16 * (n - 2));
        bptr[n] = WtE + (size_t)(colb + llo) * 128 + lhi * 8;
    }

#pragma unroll
    for (int k0 = 0; k0 < 4; ++k0) {
        bf16x8 a[2], b[4];
#pragma unroll
        for (int m = 0; m < 2; ++m) {
            int ra = 16 * m + llo;
            int byte = (ra * 256 + (k0 * 32 + lhi * 8) * 2) ^ ((ra & 7) << 4);
            a[m] = *reinterpret_cast<const bf16x8*>(lds_raw + byte);
        }
#pragma unroll
        for (int n = 0; n < 4; ++n)
            b[n] = *reinterpret_cast<const bf16x8*>(bptr[n] + k0 * 32);
#pragma unroll
        for (int m = 0; m < 2; ++m)
#pragma unroll
            for (int n = 0; n < 4; ++n)
                acc[m][n] = __builtin_amdgcn_mfma_f32_16x16x32_bf16(a[m], b[n], acc[m][n], 0, 0, 0);
    }

    const int c0 = wc * 32 + llo;
    const float bm0 = b_msg[c0], bm1 = b_msg[c0 + 16];
    const float br0 = b_rev[c0], br1 = b_rev[c0 + 16];
#pragma unroll
    for (int m = 0; m < 2; ++m) {
#pragma unroll
        for (int r = 0; r < 4; ++r) {
            int rr = 16 * m + lhi * 4 + r;
            float m0 = fmaxf(acc[m][0][r] + bm0 + bflo(gF[m][r].x) + bflo(gT[m][r].x), 0.f);
            float m1 = fmaxf(acc[m][1][r] + bm1 + bfhi(gF[m][r].x) + bfhi(gT[m][r].x), 0.f);
            float r0 = fmaxf(acc[m][2][r] + br0 + bflo(gF[m][r].y) + bflo(gT[m][r].y), 0.f);
            float r1 = fmaxf(acc[m][3][r] + br1 + bfhi(gF[m][r].y) + bfhi(gT[m][r].y), 0.f);
            msgs_u[(size_t)s_inv[rr] * 64 + wli] = bfpack(m0 + r0, m1 + r1);
        }
    }
}

// ===========================================================================
// Node update (CSR segsum of packed msgs -> MFMA w/ pi-baked WtU)
// ===========================================================================
__global__ __launch_bounds__(256, 4)
void node_upd_kernel(const unsigned int* __restrict__ msgs_u,
                     const int* __restrict__ row_start,
                     const float* __restrict__ nodef,
                     const bf16_t* __restrict__ WtU,
                     const float* __restrict__ b_upd,
                     float* __restrict__ out) {
    __shared__ char lds_raw[64 * 256];
    __shared__ int s_rs[65];

    const int tid = threadIdx.x;
    const int nb = blockIdx.x * 64;

    if (tid < 65) {
        int nid = nb + tid;
        s_rs[tid] = (nid <= N_NODES) ? row_start[nid] : N_EDGES;
    }
    __syncthreads();

    {
        const int r = tid >> 2;
        const int q = tid & 3;
        float s[32];
#pragma unroll
        for (int i = 0; i < 32; ++i) s[i] = 0.f;
        const int rs = s_rs[r], re = s_rs[r + 1];
        for (int e = rs; e < re; ++e) {
            const u32x4* p = reinterpret_cast<const u32x4*>(msgs_u + (size_t)e * 64 + q * 16);
#pragma unroll
            for (int i = 0; i < 4; ++i) {
                u32x4 w = p[i];
                s[8*i+0] += bflo(w[0]); s[8*i+1] += bfhi(w[0]);
                s[8*i+2] += bflo(w[1]); s[8*i+3] += bfhi(w[1]);
                s[8*i+4] += bflo(w[2]); s[8*i+5] += bfhi(w[2]);
                s[8*i+6] += bflo(w[3]); s[8*i+7] += bfhi(w[3]);
            }
        }
#pragma unroll
        for (int i = 0; i < 4; ++i) {
            union { bf16_t b[8]; u32x4 u; } pk;
#pragma unroll
            for (int w = 0; w < 8; ++w) pk.b[w] = (bf16_t)s[8*i + w];
            int byte = (r * 256 + q * 64 + i * 16) ^ ((r & 7) << 4);
            *reinterpret_cast<u32x4*>(lds_raw + byte) = pk.u;
        }
    }
    __syncthreads();

    const int wv = tid >> 6;
    const int lane = tid & 63;
    const int lhi = lane >> 4, llo = lane & 15;

    f32x4 acc[4][2];
#pragma unroll
    for (int m = 0; m < 4; ++m)
#pragma unroll
        for (int n = 0; n < 2; ++n)
            acc[m][n] = (f32x4){0.f, 0.f, 0.f, 0.f};

#pragma unroll
    for (int k0 = 0; k0 < 4; ++k0) {
        bf16x8 a[4], b[2];
#pragma unroll
        for (int m = 0; m < 4; ++m) {
            int ra = 16 * m + llo;
            int byte = (ra * 256 + (k0 * 32 + lhi * 8) * 2) ^ ((ra & 7) << 4);
            a[m] = *reinterpret_cast<const bf16x8*>(lds_raw + byte);
        }
#pragma unroll
        for (int n = 0; n < 2; ++n) {
            int col = wv * 32 + 16 * n + llo;
            b[n] = *reinterpret_cast<const bf16x8*>(WtU + (size_t)col * 128 + k0 * 32 + lhi * 8);
        }
#pragma unroll
        for (int m = 0; m < 4; ++m)
#pragma unroll
            for (int n = 0; n < 2; ++n)
                acc[m][n] = __builtin_amdgcn_mfma_f32_16x16x32_bf16(a[m], b[n], acc[m][n], 0, 0, 0);
    }

#pragma unroll
    for (int m = 0; m < 4; ++m) {
        int rbase = 16 * m + lhi * 4;
#pragma unroll
        for (int r = 0; r < 4; ++r) {
            int i = nb + rbase + r;
            if (i < N_NODES) {
#pragma unroll
                for (int n = 0; n < 2; ++n) {
                    int c = wv * 32 + 16 * n + llo;
                    out[(size_t)i * 128 + c] =
                        nodef[(size_t)i * 128 + c]
                        + fmaxf(acc[m][n][r] + b_upd[c], 0.f);
                }
            }
        }
    }
}

// ===========================================================================
extern "C" void kernel_launch(void* const* d_in, const int* in_sizes, int n_in,
                              void* d_out, int out_size, void* d_ws, size_t ws_size,
                              hipStream_t stream) {
    const float* nodef    = (const float*)d_in[0];
    const float* edgef    = (const float*)d_in[1];
    const int*   from_idx = (const int*)d_in[2];
    const int*   to_idx   = (const int*)d_in[3];
    const float* Wmsg     = (const float*)d_in[4];
    const float* bmsg     = (const float*)d_in[5];
    const float* Wrev     = (const float*)d_in[6];
    const float* brev     = (const float*)d_in[7];
    const float* Wupd     = (const float*)d_in[8];
    const float* bupd     = (const float*)d_in[9];
    float* out = (float*)d_out;
    char* ws = (char*)d_ws;

    unsigned int* A_u      = (unsigned int*)ws;               // 102,400,000
    unsigned int* msgs_u   = (unsigned int*)(ws + 102400000); // 163,840,000
    bf16_t*       Wt1      = (bf16_t*)(ws + 266240000);       // 131,072
    bf16_t*       WtE      = (bf16_t*)(ws + 266371072);       // 65,536
    bf16_t*       WtU      = (bf16_t*)(ws + 266436608);       // 32,768
    int*          hist     = (int*)(ws + 266469376);          // 400,000
    int*          cursor   = (int*)(ws + 266869376);          // 400,000
    int*          rowstart = (int*)(ws + 267269376);          // 400,016
    int*          inv      = (int*)(ws + 267669392);          // 2,560,000
    int*          bsum     = (int*)(ws + 270229392);          // 400
    int*          bbase    = (int*)(ws + 270229792);          // 400

    hipMemsetAsync(hist, 0, (size_t)N_NODES * sizeof(int), stream);
    prep_w_new<<<256, 256, 0, stream>>>(Wmsg, Wrev, Wupd, Wt1, WtE, WtU);
    hist_kernel<<<(N_EDGES + 255) / 256, 256, 0, stream>>>(to_idx, hist);
    scan_reduce_kernel<<<100, 1024, 0, stream>>>(hist, bsum);
    scan_base_kernel<<<1, 128, 0, stream>>>(bsum, bbase);
    scan_final_kernel<<<100, 1024, 0, stream>>>(hist, bbase, cursor, rowstart);
    inv_scatter_kernel<<<(N_EDGES + 255) / 256, 256, 0, stream>>>(to_idx, cursor, inv);
    proj_node_kernel<<<dim3((N_NODES + 63) / 64, 2), 512, 0, stream>>>(nodef, Wt1, A_u);
    edge_fused_kernel<<<N_EDGES / 32, 256, 0, stream>>>(
        edgef, from_idx, to_idx, inv, A_u, WtE, bmsg, brev, msgs_u);
    node_upd_kernel<<<(N_NODES + 63) / 64, 256, 0, stream>>>(
        msgs_u, rowstart, nodef, WtU, bupd, out);
}